// Round 15
// baseline (429.254 us; speedup 1.0000x reference)
//
#include <hip/hip_runtime.h>
#include <stdint.h>

#define DEV static __device__ __forceinline__

typedef unsigned short u16;
typedef unsigned int u32;
typedef __attribute__((ext_vector_type(4))) float f32x4;
typedef __attribute__((ext_vector_type(8))) short bf16x8;

DEV float bf2f(u16 u) { u32 x = ((u32)u) << 16; float f; __builtin_memcpy(&f, &x, 4); return f; }
DEV u16 f2bf(float f) { u32 x; __builtin_memcpy(&x, &f, 4); x = x + 0x7fffu + ((x >> 16) & 1u); return (u16)(x >> 16); }
DEV float lo16(u32 p) { u32 x = p << 16; float f; __builtin_memcpy(&f, &x, 4); return f; }
DEV float hi16(u32 p) { u32 x = p & 0xffff0000u; float f; __builtin_memcpy(&f, &x, 4); return f; }

DEV u32 cvtpk(float lo, float hi) {        // one v_cvt_pk_bf16_f32 (no builtin on gfx950)
  u32 r; asm("v_cvt_pk_bf16_f32 %0, %1, %2" : "=v"(r) : "v"(lo), "v"(hi)); return r;
}
DEV bf16x8 pk8(f32x4 a, f32x4 b) {
  union { u32 u[4]; bf16x8 v; } x;
  x.u[0] = cvtpk(a[0], a[1]); x.u[1] = cvtpk(a[2], a[3]);
  x.u[2] = cvtpk(b[0], b[1]); x.u[3] = cvtpk(b[2], b[3]);
  return x.v;
}

DEV f32x4 mfma16(bf16x8 a, bf16x8 b, f32x4 c) {
  return __builtin_amdgcn_mfma_f32_16x16x32_bf16(a, b, c, 0, 0, 0);
}

DEV void gl_lds16(const u16* g, u16* l) {
  __builtin_amdgcn_global_load_lds((const __attribute__((address_space(1))) void*)g,
                                   (__attribute__((address_space(3))) void*)l, 16, 0, 0);
}

// ---------------- merged: weight prep (casts + Wq group-sum + rope table) AND 3x layernorm -----------
// blocks 0..6143: weight casts; 6144..6399: rope table; 6400..55551: LN rows (3 x 16384).
__global__ __launch_bounds__(256) void prep_ln_kernel(
    const float* __restrict__ Wq, const float* __restrict__ Wk, const float* __restrict__ Wv,
    const float* __restrict__ Wo, const float* __restrict__ Wkc, const float* __restrict__ Wvc,
    u16* __restrict__ wqe, u16* __restrict__ wkb, u16* __restrict__ wvb,
    u16* __restrict__ wob, u16* __restrict__ wkcb, u16* __restrict__ wvcb,
    float* __restrict__ cs,
    const float* __restrict__ xq, const float* __restrict__ xk, const float* __restrict__ xv,
    const float* __restrict__ lnw, const float* __restrict__ lnb,
    u16* __restrict__ oq, u16* __restrict__ ok, u16* __restrict__ ov) {
  int b = blockIdx.x;
  if (b < 6144) {
    int which = b >> 10;                             // 0..5
    int id = (b & 1023) * 256 + threadIdx.x;         // 262144 float4 units each
    const float* src; u16* dst;
    switch (which) {
      case 0: src = Wq;  dst = wqe;  break;
      case 1: src = Wk;  dst = wkb;  break;
      case 2: src = Wv;  dst = wvb;  break;
      case 3: src = Wo;  dst = wob;  break;
      case 4: src = Wkc; dst = wkcb; break;
      default: src = Wvc; dst = wvcb; break;
    }
    float4 a = ((const float4*)src)[id];
    if (which == 0) {
      float4 c = ((const float4*)Wq)[id + 262144];   // second GQA group slice
      a.x += c.x; a.y += c.y; a.z += c.z; a.w += c.w;
    }
    ushort4 o; o.x = f2bf(a.x); o.y = f2bf(a.y); o.z = f2bf(a.z); o.w = f2bf(a.w);
    ((ushort4*)dst)[id] = o;
    return;
  }
  if (b < 6400) {
    int id = (b - 6144) * 256 + threadIdx.x;         // 65536 = 2048*32
    int t = id >> 5, i = id & 31;
    double ang = (double)t * pow(10000.0, -(double)(2 * i) / 64.0);
    cs[id * 2] = (float)cos(ang);
    cs[id * 2 + 1] = (float)sin(ang);
    return;
  }
  int bq = b - 6400;
  int which = bq >> 14, row = bq & 16383;            // 3 x 16384 LN rows
  const float* x = which == 0 ? xq : (which == 1 ? xk : xv);
  u16* out = which == 0 ? oq : (which == 1 ? ok : ov);
  int t = threadIdx.x;
  float4 v = ((const float4*)(x + (size_t)row * 1024))[t];
  float s = v.x + v.y + v.z + v.w;
  float s2 = v.x * v.x + v.y * v.y + v.z * v.z + v.w * v.w;
#pragma unroll
  for (int off = 32; off; off >>= 1) { s += __shfl_xor(s, off, 64); s2 += __shfl_xor(s2, off, 64); }
  __shared__ float red[8];
  if ((t & 63) == 0) { red[t >> 6] = s; red[4 + (t >> 6)] = s2; }
  __syncthreads();
  s = red[0] + red[1] + red[2] + red[3];
  s2 = red[4] + red[5] + red[6] + red[7];
  float mu = s * 0.0009765625f;
  float var = s2 * 0.0009765625f - mu * mu;
  float rstd = rsqrtf(var + 1e-5f);
  float4 wv = ((const float4*)lnw)[t];
  float4 bv = ((const float4*)lnb)[t];
  ushort4 o;
  o.x = f2bf((v.x - mu) * rstd * wv.x + bv.x);
  o.y = f2bf((v.y - mu) * rstd * wv.y + bv.y);
  o.z = f2bf((v.z - mu) * rstd * wv.z + bv.z);
  o.w = f2bf((v.w - mu) * rstd * wv.w + bv.w);
  *(ushort4*)(out + (size_t)row * 1024 + t * 4) = o;
}

// ---------------- batched QKV NT GEMM: z selects (A,B,C,rope)  (256x128 tile, BK=64, 512 thr) ---------
// 8 waves as 4M x 2N (64x64 per wave). Grid (x = M/256, y = N/128, z = 3); bid%8 = x%8 pins the
// A row-band to one XCD. XOR swizzle on both global source and read side.
__global__ __launch_bounds__(512, 4) void gemm_qkv(
    const u16* __restrict__ Aq, const u16* __restrict__ Ak, const u16* __restrict__ Av,
    const u16* __restrict__ Bq, const u16* __restrict__ Bk, const u16* __restrict__ Bv,
    u16* __restrict__ Cq, u16* __restrict__ Ck, u16* __restrict__ Cv,
    const float* __restrict__ cs) {
  const int K = 1024, Nd = 1024;
  int z = blockIdx.z;
  const u16* A = z == 0 ? Aq : (z == 1 ? Ak : Av);
  const u16* B = z == 0 ? Bq : (z == 1 ? Bk : Bv);
  u16* C = z == 0 ? Cq : (z == 1 ? Ck : Cv);
  bool dorope = (z < 2);
  __shared__ u16 As[16384], Bs[8192];                // A: [256 rows][64 k], B: [128 rows][64 k]
  int tid = threadIdx.x, lane = tid & 63, wv = tid >> 6;   // wv 0..7
  int l15 = lane & 15, lq = lane >> 4;
  int bm = blockIdx.x * 256, bn = blockIdx.y * 128;
  int wm = (wv >> 1) * 64, wn = (wv & 1) * 64;
  int srow_in = lane >> 3, sslot = lane & 7;
  f32x4 acc[4][4] = {};
  for (int k0 = 0; k0 < K; k0 += 64) {
    __syncthreads();                                 // previous iter's LDS reads done
#pragma unroll
    for (int it = 0; it < 4; ++it) {                 // A: 32 slabs (8 rows x 64k each)
      int ia = it * 8 + wv;
      int row = ia * 8 + srow_in;                    // 0..255
      int gc = sslot ^ (row & 7);                    // pre-swizzled global chunk
      gl_lds16(A + (size_t)(bm + row) * K + k0 + gc * 8, &As[ia * 512]);
    }
#pragma unroll
    for (int it = 0; it < 2; ++it) {                 // B: 16 slabs
      int ia = it * 8 + wv;
      int row = ia * 8 + srow_in;                    // 0..127
      int gc = sslot ^ (row & 7);
      gl_lds16(B + (size_t)(bn + row) * K + k0 + gc * 8, &Bs[ia * 512]);
    }
    __syncthreads();                                 // vmcnt(0) drain before use
#pragma unroll
    for (int h = 0; h < 2; ++h) {
      bf16x8 af[4], bfr[4];
#pragma unroll
      for (int mt = 0; mt < 4; ++mt) {
        int r = wm + mt * 16 + l15;
        af[mt] = *(const bf16x8*)&As[r * 64 + (((h * 4 + lq) ^ (r & 7)) * 8)];
      }
#pragma unroll
      for (int nt = 0; nt < 4; ++nt) {
        int r = wn + nt * 16 + l15;
        bfr[nt] = *(const bf16x8*)&Bs[r * 64 + (((h * 4 + lq) ^ (r & 7)) * 8)];
      }
#pragma unroll
      for (int mt = 0; mt < 4; ++mt)
#pragma unroll
        for (int nt = 0; nt < 4; ++nt)
          acc[mt][nt] = mfma16(af[mt], bfr[nt], acc[mt][nt]);
    }
  }
#pragma unroll
  for (int mt = 0; mt < 4; ++mt)
#pragma unroll
    for (int nt = 0; nt < 4; ++nt)
#pragma unroll
      for (int i = 0; i < 4; ++i) {
        int row = bm + wm + mt * 16 + lq * 4 + i;
        int col = bn + wn + nt * 16 + l15;
        float x = acc[mt][nt][i];
        if (dorope) {
          float xp = __shfl_xor(x, 1, 64);           // partner column (col^1), lane l15^1
          int t = row & 2047;
          int i0 = (col & 63) >> 1;
          float2 csv = *(const float2*)(cs + ((size_t)t * 32 + i0) * 2);
          x = (col & 1) ? (x * csv.x + xp * csv.y) : (x * csv.x - xp * csv.y);
        }
        C[(size_t)row * Nd + col] = f2bf(x);
      }
}

// ---------------- output NT GEMM (f32 out), same 256x128 structure ----------------
__global__ __launch_bounds__(512, 4) void gemm_out(const u16* __restrict__ A, const u16* __restrict__ B,
                                                   float* __restrict__ Cout) {
  const int K = 1024, Nd = 1024;
  __shared__ u16 As[16384], Bs[8192];
  int tid = threadIdx.x, lane = tid & 63, wv = tid >> 6;
  int l15 = lane & 15, lq = lane >> 4;
  int bm = blockIdx.x * 256, bn = blockIdx.y * 128;
  int wm = (wv >> 1) * 64, wn = (wv & 1) * 64;
  int srow_in = lane >> 3, sslot = lane & 7;
  f32x4 acc[4][4] = {};
  for (int k0 = 0; k0 < K; k0 += 64) {
    __syncthreads();
#pragma unroll
    for (int it = 0; it < 4; ++it) {
      int ia = it * 8 + wv;
      int row = ia * 8 + srow_in;
      int gc = sslot ^ (row & 7);
      gl_lds16(A + (size_t)(bm + row) * K + k0 + gc * 8, &As[ia * 512]);
    }
#pragma unroll
    for (int it = 0; it < 2; ++it) {
      int ia = it * 8 + wv;
      int row = ia * 8 + srow_in;
      int gc = sslot ^ (row & 7);
      gl_lds16(B + (size_t)(bn + row) * K + k0 + gc * 8, &Bs[ia * 512]);
    }
    __syncthreads();
#pragma unroll
    for (int h = 0; h < 2; ++h) {
      bf16x8 af[4], bfr[4];
#pragma unroll
      for (int mt = 0; mt < 4; ++mt) {
        int r = wm + mt * 16 + l15;
        af[mt] = *(const bf16x8*)&As[r * 64 + (((h * 4 + lq) ^ (r & 7)) * 8)];
      }
#pragma unroll
      for (int nt = 0; nt < 4; ++nt) {
        int r = wn + nt * 16 + l15;
        bfr[nt] = *(const bf16x8*)&Bs[r * 64 + (((h * 4 + lq) ^ (r & 7)) * 8)];
      }
#pragma unroll
      for (int mt = 0; mt < 4; ++mt)
#pragma unroll
        for (int nt = 0; nt < 4; ++nt)
          acc[mt][nt] = mfma16(af[mt], bfr[nt], acc[mt][nt]);
    }
  }
#pragma unroll
  for (int mt = 0; mt < 4; ++mt)
#pragma unroll
    for (int nt = 0; nt < 4; ++nt)
#pragma unroll
      for (int i = 0; i < 4; ++i) {
        int row = bm + wm + mt * 16 + lq * 4 + i;
        int col = bn + wn + nt * 16 + l15;
        Cout[(size_t)row * Nd + col] = acc[mt][nt][i];
      }
}

// ---------------- segment compression, split-K MFMA (stage 1: partials) ----------------
__global__ __launch_bounds__(512) void compress_partial_kernel(
    const u16* __restrict__ kh, const u16* __restrict__ vh,
    const u16* __restrict__ wkcb, const u16* __restrict__ wvcb,
    float* __restrict__ part) {
  int mt = blockIdx.x, ksl = blockIdx.y, kv = blockIdx.z;
  const u16* src = kv ? vh : kh;
  const u16* W = kv ? wvcb : wkcb;
  int tid = threadIdx.x, lane = tid & 63, wv = tid >> 6;
  int l15 = lane & 15, lq = lane >> 4;
  int r = mt * 16 + l15;                             // row in [0,768)
  int nh = r / 6, s = r % 6;
  int n = nh >> 4, h = nh & 15;
  const u16* arow = src + ((size_t)(n * 2048 + s * 256)) * 1024 + h * 64;
  f32x4 acc[4] = {};
  int kbase = (ksl * 8 + wv) * 256;
#pragma unroll
  for (int ks = 0; ks < 8; ++ks) {
    int k0 = kbase + ks * 32;
    int tau = k0 >> 6, d0 = k0 & 63;
    bf16x8 a = *(const bf16x8*)(arow + (size_t)tau * 1024 + d0 + lq * 8);
#pragma unroll
    for (int nt = 0; nt < 4; ++nt) {
      bf16x8 b = *(const bf16x8*)(W + (size_t)(nt * 16 + l15) * 16384 + k0 + lq * 8);
      acc[nt] = mfma16(a, b, acc[nt]);
    }
  }
  __shared__ float red[8][16][68];                   // 68-stride: 2-way bank alias only (free)
#pragma unroll
  for (int nt = 0; nt < 4; ++nt)
#pragma unroll
    for (int i = 0; i < 4; ++i)
      red[wv][lq * 4 + i][nt * 16 + l15] = acc[nt][i];
  __syncthreads();
  int row = tid >> 5, o0 = (tid & 31) * 2;           // 512 threads -> 16 rows x 32 pairs
  float v0 = 0.f, v1 = 0.f;
#pragma unroll
  for (int w8 = 0; w8 < 8; ++w8) { v0 += red[w8][row][o0]; v1 += red[w8][row][o0 + 1]; }
  size_t base = ((size_t)(kv * 8 + ksl) * 768 + mt * 16 + row) * 64 + o0;
  part[base] = v0;
  part[base + 1] = v1;
}

// ---------------- merged: compress finalize (sum slices, bias, elu, scatter) + copy recent ------------
__global__ __launch_bounds__(256) void finalize_copy_kernel(
    const float* __restrict__ part, const float* __restrict__ bkc, const float* __restrict__ bvc,
    const u16* __restrict__ kh, const u16* __restrict__ vh,
    u16* __restrict__ kp, u16* __restrict__ vtp) {
  int bid = blockIdx.x;
  if (bid < 2280) {                                  // K rows T=6..575
    int u = bid * 256 + threadIdx.x;                 // = (nh*570 + (T-6))*8 + dq8
    int dq8 = u & 7; int rest = u >> 3; int Tm6 = rest % 570; int nh = rest / 570;
    if (nh >= 128) return;
    uint4 val = {0, 0, 0, 0};
    if (Tm6 < 512) {
      int n = nh >> 4, h = nh & 15;
      val = *(const uint4*)&kh[((size_t)(n * 2048 + 1536 + Tm6)) * 1024 + h * 64 + dq8 * 8];
    }
    *(uint4*)&kp[((size_t)nh * 576 + 6 + Tm6) * 64 + dq8 * 8] = val;
  } else if (bid < 4584) {                           // V^T cols
    int u = (bid - 2280) * 256 + threadIdx.x;        // = (nh*72 + tch)*64 + d
    int d = u & 63; int rest = u >> 6; int tch = rest % 72; int nh = rest / 72;
    if (nh >= 128) return;
    int n = nh >> 4, h = nh & 15;
#pragma unroll
    for (int ii = 0; ii < 8; ++ii) {
      int T = tch * 8 + ii;
      if (T < 6) continue;                           // written by compression
      u16 v = 0;
      if (T < 518) v = vh[((size_t)(n * 2048 + 1536 + (T - 6))) * 1024 + h * 64 + d];
      vtp[((size_t)nh * 64 + d) * 576 + T] = v;
    }
  } else {                                           // compress finalize
    int b2 = bid - 4584;                             // 0..383
    int kv = b2 >= 192;
    int id = (kv ? b2 - 192 : b2) * 256 + threadIdx.x;   // [0, 49152)
    int r = id >> 6, o = id & 63;
    float v = kv ? bvc[o] : bkc[o];
#pragma unroll
    for (int s8 = 0; s8 < 8; ++s8) v += part[((size_t)(kv * 8 + s8) * 768 + r) * 64 + o];
    v = v > 0.f ? v : expm1f(v);                     // elu
    int nh = r / 6, s = r % 6;
    if (kv) vtp[((size_t)nh * 64 + o) * 576 + s] = f2bf(v);
    else    kp[((size_t)nh * 576 + s) * 64 + o] = f2bf(v);
  }
}

// ---------------- fused attention: per (n,h,128 q-rows), 512 thr / 8 waves x 16 rows each --------------
// Fixed softmax max=30; XCD-pinning grid (h, qt, n); causal wave skip.
__global__ __launch_bounds__(512) void attn_kernel(const u16* __restrict__ qc, const u16* __restrict__ Kp,
                                                   const u16* __restrict__ VTp, u16* __restrict__ ao) {
  int h = blockIdx.x, qt = blockIdx.y, n = blockIdx.z;
  int tid = threadIdx.x, lane = tid & 63, wv = tid >> 6;   // wv 0..7
  int l15 = lane & 15, lq = lane >> 4;
  __shared__ u16 KS[4096], VS[4096];                 // 64x64 bf16 chunks, row-XOR-swizzled
  __shared__ float PS[8][1088];                      // per-wave P [16 rows][68 f32]
  int q0 = qt * 128 + wv * 16;
  const u16* qrowp = qc + ((size_t)(n * 2048 + q0 + l15)) * 1024 + h * 64;
  bf16x8 aq0 = *(const bf16x8*)(qrowp + lq * 8);
  bf16x8 aq1 = *(const bf16x8*)(qrowp + 32 + lq * 8);
  const u16* Kph = Kp + (size_t)(n * 16 + h) * 576 * 64;
  const u16* Vph = VTp + (size_t)(n * 16 + h) * 64 * 576;
  f32x4 oa[4] = {};
  float rs[4] = {0.f, 0.f, 0.f, 0.f};
  float* PSW = &PS[wv][0];
  const float C1 = 0.012022458674074693f;            // 0.125 * (2/30) * log2(e)
  const float C2 = -86.56170245333781f;              // -60 * log2(e)
  int nchunks = min(2 * qt + 2, 9);                  // block rows < 128(qt+1)
  int dcw = 2 * qt + (wv >> 2);                      // wave's diagonal chunk
  int srow = tid >> 3, sq = tid & 7;
  int ksw = srow * 64 + ((sq ^ (srow & 7)) * 8);
  uint4 kr, vr;
  {
    kr = *(const uint4*)&Kph[(size_t)srow * 64 + sq * 8];
    vr = *(const uint4*)&Vph[(size_t)srow * 576 + sq * 8];
  }
  for (int tc = 0; tc < nchunks; ++tc) {
    __syncthreads();                                 // prev iter's LDS reads done
    *(uint4*)&KS[ksw] = kr;
    *(uint4*)&VS[ksw] = vr;
    if (tc + 1 < nchunks) {                          // async prefetch of next chunk
      int Tb = (tc + 1) * 64;
      kr = *(const uint4*)&Kph[(size_t)(Tb + srow) * 64 + sq * 8];
      vr = *(const uint4*)&Vph[(size_t)srow * 576 + Tb + sq * 8];
    }
    __syncthreads();                                 // LDS writes visible
    if (tc > dcw) continue;                          // wave-uniform causal skip
    f32x4 sv[4];
    __builtin_amdgcn_s_setprio(1);
#pragma unroll
    for (int tt = 0; tt < 4; ++tt) {
      int row = tt * 16 + l15, r7 = row & 7;
      bf16x8 b0 = *(const bf16x8*)&KS[row * 64 + ((lq ^ r7) * 8)];
      bf16x8 b1 = *(const bf16x8*)&KS[row * 64 + (((4 | lq) ^ r7) * 8)];
      f32x4 c = {0.f, 0.f, 0.f, 0.f};
      c = mfma16(aq0, b0, c);
      c = mfma16(aq1, b1, c);
      sv[tt] = c;
    }
    __builtin_amdgcn_s_setprio(0);
    float p[4][4];
    bool needmask = (tc == dcw) || (tc == 8);
    if (needmask) {
      int qb = q0 + lq * 4;
      int Tbase = tc * 64;
#pragma unroll
      for (int tt = 0; tt < 4; ++tt) {
        int T = Tbase + tt * 16 + l15;
        bool tval = (T < 518);
#pragma unroll
        for (int i = 0; i < 4; ++i) {
          float e = __builtin_amdgcn_exp2f(sv[tt][i] * C1);
          float pe = __builtin_amdgcn_exp2f(C2 * __builtin_amdgcn_rcpf(e + 1.f));
          bool ok = tval && (T <= qb + i);
          pe = ok ? pe : 0.f;
          p[tt][i] = pe;
          rs[i] += pe;
        }
      }
    } else {
#pragma unroll
      for (int tt = 0; tt < 4; ++tt)
#pragma unroll
        for (int i = 0; i < 4; ++i) {
          float e = __builtin_amdgcn_exp2f(sv[tt][i] * C1);
          float pe = __builtin_amdgcn_exp2f(C2 * __builtin_amdgcn_rcpf(e + 1.f));
          p[tt][i] = pe;
          rs[i] += pe;
        }
    }
#pragma unroll
    for (int tt = 0; tt < 4; ++tt)
#pragma unroll
      for (int i = 0; i < 4; ++i)
        PSW[(lq * 4 + i) * 68 + tt * 16 + l15] = p[tt][i];
    const float* prow = PSW + l15 * 68;
    f32x4 r0a = *(const f32x4*)(prow + lq * 8);
    f32x4 r0b = *(const f32x4*)(prow + lq * 8 + 4);
    f32x4 r1a = *(const f32x4*)(prow + lq * 8 + 32);
    f32x4 r1b = *(const f32x4*)(prow + lq * 8 + 36);
    bf16x8 pa0 = pk8(r0a, r0b);
    bf16x8 pa1 = pk8(r1a, r1b);
    __builtin_amdgcn_s_setprio(1);
#pragma unroll
    for (int ct = 0; ct < 4; ++ct) {
      int row = ct * 16 + l15, r7 = row & 7;
      bf16x8 bv0 = *(const bf16x8*)&VS[row * 64 + ((lq ^ r7) * 8)];
      bf16x8 bv1 = *(const bf16x8*)&VS[row * 64 + (((4 | lq) ^ r7) * 8)];
      oa[ct] = mfma16(pa0, bv0, oa[ct]);
      oa[ct] = mfma16(pa1, bv1, oa[ct]);
    }
    __builtin_amdgcn_s_setprio(0);
  }
#pragma unroll
  for (int i = 0; i < 4; ++i)
#pragma unroll
    for (int off = 1; off < 16; off <<= 1) rs[i] += __shfl_xor(rs[i], off, 64);
  u16* aop = ao + ((size_t)(n * 2048)) * 1024 + h * 64;
#pragma unroll
  for (int i = 0; i < 4; ++i) {
    float inv = 1.0f / rs[i];
    int q = q0 + lq * 4 + i;
#pragma unroll
    for (int ct = 0; ct < 4; ++ct) {
      int dv = ct * 16 + l15;
      aop[(size_t)q * 1024 + dv] = f2bf(oa[ct][i] * inv);
    }
  }
}

extern "C" void kernel_launch(void* const* d_in, const int* in_sizes, int n_in,
                              void* d_out, int out_size, void* d_ws, size_t ws_size,
                              hipStream_t stream) {
  const float* q_in = (const float*)d_in[0];
  const float* k_in = (const float*)d_in[1];
  const float* v_in = (const float*)d_in[2];
  const float* ln_w = (const float*)d_in[3];
  const float* ln_b = (const float*)d_in[4];
  const float* Wq = (const float*)d_in[5];
  const float* Wk = (const float*)d_in[6];
  const float* Wv = (const float*)d_in[7];
  const float* Wo = (const float*)d_in[8];
  const float* Wkc = (const float*)d_in[9];
  const float* bkc = (const float*)d_in[10];
  const float* Wvc = (const float*)d_in[11];
  const float* bvc = (const float*)d_in[12];

  char* ws = (char*)d_ws;
  const size_t MB = 1u << 20;
  u16* wqe = (u16*)(ws + 0 * MB);
  u16* wkb = (u16*)(ws + 2 * MB);
  u16* wvb = (u16*)(ws + 4 * MB);
  u16* wob = (u16*)(ws + 6 * MB);
  u16* wkcb = (u16*)(ws + 8 * MB);
  u16* wvcb = (u16*)(ws + 10 * MB);
  float* csb = (float*)(ws + 12 * MB);   // 512KB float2 cos/sin table
  u16* xn = (u16*)(ws + 13 * MB);    // 32MB: LN(v) staging; dead after gemm-v -> reused for partials
  float* partf = (float*)(ws + 13 * MB);
  u16* qcb = (u16*)(ws + 45 * MB);   // 32MB
  u16* khb = (u16*)(ws + 77 * MB);   // 32MB
  u16* vhb = (u16*)(ws + 109 * MB);  // 32MB
  u16* kp = (u16*)(ws + 141 * MB);   // 9.0MB
  u16* vtp = (u16*)(ws + 141 * MB + 9437184);
  u16* aob = khb;                    // kh dead once attention runs
  // d_out (64MB f32) doubles as LN scratch for q and k (2 x 32MB bf16);
  // the final GEMM fully overwrites it.
  u16* xq = (u16*)d_out;
  u16* xk = ((u16*)d_out) + 16777216;

  // merged weight prep + 3x layernorm (one launch)
  prep_ln_kernel<<<55552, 256, 0, stream>>>(Wq, Wk, Wv, Wo, Wkc, Wvc,
                                            wqe, wkb, wvb, wob, wkcb, wvcb, csb,
                                            q_in, k_in, v_in, ln_w, ln_b, xq, xk, xn);

  // batched Q/K/V projections (+RoPE on q,k) in one launch
  gemm_qkv<<<dim3(64, 8, 3), 512, 0, stream>>>(xq, xk, xn, wqe, wkb, wvb, qcb, khb, vhb, csb);

  compress_partial_kernel<<<dim3(48, 8, 2), 512, 0, stream>>>(khb, vhb, wkcb, wvcb, partf);
  finalize_copy_kernel<<<4968, 256, 0, stream>>>(partf, bkc, bvc, khb, vhb, kp, vtp);
  attn_kernel<<<dim3(16, 16, 8), 512, 0, stream>>>(qcb, kp, vtp, aob);
  gemm_out<<<dim3(64, 8), 512, 0, stream>>>(aob, wob, (float*)d_out);
}

// Round 16
// 375.921 us; speedup vs baseline: 1.1419x; 1.1419x over previous
//
#include <hip/hip_runtime.h>
#include <stdint.h>

#define DEV static __device__ __forceinline__

typedef unsigned short u16;
typedef unsigned int u32;
typedef __attribute__((ext_vector_type(4))) float f32x4;
typedef __attribute__((ext_vector_type(8))) short bf16x8;

DEV float bf2f(u16 u) { u32 x = ((u32)u) << 16; float f; __builtin_memcpy(&f, &x, 4); return f; }
DEV u16 f2bf(float f) { u32 x; __builtin_memcpy(&x, &f, 4); x = x + 0x7fffu + ((x >> 16) & 1u); return (u16)(x >> 16); }
DEV float lo16(u32 p) { u32 x = p << 16; float f; __builtin_memcpy(&f, &x, 4); return f; }
DEV float hi16(u32 p) { u32 x = p & 0xffff0000u; float f; __builtin_memcpy(&f, &x, 4); return f; }

DEV u32 cvtpk(float lo, float hi) {        // one v_cvt_pk_bf16_f32 (no builtin on gfx950)
  u32 r; asm("v_cvt_pk_bf16_f32 %0, %1, %2" : "=v"(r) : "v"(lo), "v"(hi)); return r;
}
DEV bf16x8 pk8(f32x4 a, f32x4 b) {
  union { u32 u[4]; bf16x8 v; } x;
  x.u[0] = cvtpk(a[0], a[1]); x.u[1] = cvtpk(a[2], a[3]);
  x.u[2] = cvtpk(b[0], b[1]); x.u[3] = cvtpk(b[2], b[3]);
  return x.v;
}

DEV f32x4 mfma16(bf16x8 a, bf16x8 b, f32x4 c) {
  return __builtin_amdgcn_mfma_f32_16x16x32_bf16(a, b, c, 0, 0, 0);
}

DEV void gl_lds16(const u16* g, u16* l) {
  __builtin_amdgcn_global_load_lds((const __attribute__((address_space(1))) void*)g,
                                   (__attribute__((address_space(3))) void*)l, 16, 0, 0);
}

// ---------------- merged: weight prep (casts + Wq group-sum + rope table) AND 3x layernorm -----------
// blocks 0..6143: weight casts; 6144..6399: rope table; 6400..55551: LN rows (3 x 16384).
__global__ __launch_bounds__(256) void prep_ln_kernel(
    const float* __restrict__ Wq, const float* __restrict__ Wk, const float* __restrict__ Wv,
    const float* __restrict__ Wo, const float* __restrict__ Wkc, const float* __restrict__ Wvc,
    u16* __restrict__ wqe, u16* __restrict__ wkb, u16* __restrict__ wvb,
    u16* __restrict__ wob, u16* __restrict__ wkcb, u16* __restrict__ wvcb,
    float* __restrict__ cs,
    const float* __restrict__ xq, const float* __restrict__ xk, const float* __restrict__ xv,
    const float* __restrict__ lnw, const float* __restrict__ lnb,
    u16* __restrict__ oq, u16* __restrict__ ok, u16* __restrict__ ov) {
  int b = blockIdx.x;
  if (b < 6144) {
    int which = b >> 10;                             // 0..5
    int id = (b & 1023) * 256 + threadIdx.x;         // 262144 float4 units each
    const float* src; u16* dst;
    switch (which) {
      case 0: src = Wq;  dst = wqe;  break;
      case 1: src = Wk;  dst = wkb;  break;
      case 2: src = Wv;  dst = wvb;  break;
      case 3: src = Wo;  dst = wob;  break;
      case 4: src = Wkc; dst = wkcb; break;
      default: src = Wvc; dst = wvcb; break;
    }
    float4 a = ((const float4*)src)[id];
    if (which == 0) {
      float4 c = ((const float4*)Wq)[id + 262144];   // second GQA group slice
      a.x += c.x; a.y += c.y; a.z += c.z; a.w += c.w;
    }
    ushort4 o; o.x = f2bf(a.x); o.y = f2bf(a.y); o.z = f2bf(a.z); o.w = f2bf(a.w);
    ((ushort4*)dst)[id] = o;
    return;
  }
  if (b < 6400) {
    int id = (b - 6144) * 256 + threadIdx.x;         // 65536 = 2048*32
    int t = id >> 5, i = id & 31;
    double ang = (double)t * pow(10000.0, -(double)(2 * i) / 64.0);
    cs[id * 2] = (float)cos(ang);
    cs[id * 2 + 1] = (float)sin(ang);
    return;
  }
  int bq = b - 6400;
  int which = bq >> 14, row = bq & 16383;            // 3 x 16384 LN rows
  const float* x = which == 0 ? xq : (which == 1 ? xk : xv);
  u16* out = which == 0 ? oq : (which == 1 ? ok : ov);
  int t = threadIdx.x;
  float4 v = ((const float4*)(x + (size_t)row * 1024))[t];
  float s = v.x + v.y + v.z + v.w;
  float s2 = v.x * v.x + v.y * v.y + v.z * v.z + v.w * v.w;
#pragma unroll
  for (int off = 32; off; off >>= 1) { s += __shfl_xor(s, off, 64); s2 += __shfl_xor(s2, off, 64); }
  __shared__ float red[8];
  if ((t & 63) == 0) { red[t >> 6] = s; red[4 + (t >> 6)] = s2; }
  __syncthreads();
  s = red[0] + red[1] + red[2] + red[3];
  s2 = red[4] + red[5] + red[6] + red[7];
  float mu = s * 0.0009765625f;
  float var = s2 * 0.0009765625f - mu * mu;
  float rstd = rsqrtf(var + 1e-5f);
  float4 wv = ((const float4*)lnw)[t];
  float4 bv = ((const float4*)lnb)[t];
  ushort4 o;
  o.x = f2bf((v.x - mu) * rstd * wv.x + bv.x);
  o.y = f2bf((v.y - mu) * rstd * wv.y + bv.y);
  o.z = f2bf((v.z - mu) * rstd * wv.z + bv.z);
  o.w = f2bf((v.w - mu) * rstd * wv.w + bv.w);
  *(ushort4*)(out + (size_t)row * 1024 + t * 4) = o;
}

// ---------------- NT GEMM: C[m][n] = sum_k A[m*K+k]*B[n*K+k]  (256x128 tile, BK=64, 512 thr) ----------
// 8 waves as 4M x 2N (64x64 per wave). Grid (x = M/256, y = N/128); bid%8 = x%8 pins the
// A row-band to one XCD (ONE A matrix per dispatch -- batching 3 thrashed L2, round-15 lesson).
// XOR swizzle on both global source and read side.
// MODE: 0 = bf16 out, 1 = f32 out, 2 = bf16 out + fused interleaved RoPE (64-col heads, t=row%2048)
template <int MODE>
__global__ __launch_bounds__(512, 4) void gemm_nt(const u16* __restrict__ A, const u16* __restrict__ B,
                                                  void* __restrict__ Cout, int M, int Nd, int K,
                                                  const float* __restrict__ cs) {
  __shared__ u16 As[16384], Bs[8192];                // A: [256 rows][64 k], B: [128 rows][64 k]
  int tid = threadIdx.x, lane = tid & 63, wv = tid >> 6;   // wv 0..7
  int l15 = lane & 15, lq = lane >> 4;
  int bm = blockIdx.x * 256, bn = blockIdx.y * 128;
  int wm = (wv >> 1) * 64, wn = (wv & 1) * 64;
  int srow_in = lane >> 3, sslot = lane & 7;
  f32x4 acc[4][4] = {};
  for (int k0 = 0; k0 < K; k0 += 64) {
    __syncthreads();                                 // previous iter's LDS reads done
#pragma unroll
    for (int it = 0; it < 4; ++it) {                 // A: 32 slabs (8 rows x 64k each)
      int ia = it * 8 + wv;
      int row = ia * 8 + srow_in;                    // 0..255
      int gc = sslot ^ (row & 7);                    // pre-swizzled global chunk
      gl_lds16(A + (size_t)(bm + row) * K + k0 + gc * 8, &As[ia * 512]);
    }
#pragma unroll
    for (int it = 0; it < 2; ++it) {                 // B: 16 slabs
      int ia = it * 8 + wv;
      int row = ia * 8 + srow_in;                    // 0..127
      int gc = sslot ^ (row & 7);
      gl_lds16(B + (size_t)(bn + row) * K + k0 + gc * 8, &Bs[ia * 512]);
    }
    __syncthreads();                                 // vmcnt(0) drain before use
#pragma unroll
    for (int h = 0; h < 2; ++h) {
      bf16x8 af[4], bfr[4];
#pragma unroll
      for (int mt = 0; mt < 4; ++mt) {
        int r = wm + mt * 16 + l15;
        af[mt] = *(const bf16x8*)&As[r * 64 + (((h * 4 + lq) ^ (r & 7)) * 8)];
      }
#pragma unroll
      for (int nt = 0; nt < 4; ++nt) {
        int r = wn + nt * 16 + l15;
        bfr[nt] = *(const bf16x8*)&Bs[r * 64 + (((h * 4 + lq) ^ (r & 7)) * 8)];
      }
#pragma unroll
      for (int mt = 0; mt < 4; ++mt)
#pragma unroll
        for (int nt = 0; nt < 4; ++nt)
          acc[mt][nt] = mfma16(af[mt], bfr[nt], acc[mt][nt]);
    }
  }
#pragma unroll
  for (int mt = 0; mt < 4; ++mt)
#pragma unroll
    for (int nt = 0; nt < 4; ++nt)
#pragma unroll
      for (int i = 0; i < 4; ++i) {
        int row = bm + wm + mt * 16 + lq * 4 + i;
        int col = bn + wn + nt * 16 + l15;
        float x = acc[mt][nt][i];
        if (MODE == 1) {
          ((float*)Cout)[(size_t)row * Nd + col] = x;
        } else if (MODE == 0) {
          ((u16*)Cout)[(size_t)row * Nd + col] = f2bf(x);
        } else {
          float xp = __shfl_xor(x, 1, 64);           // partner column (col^1), lane l15^1
          int t = row & 2047;
          int i0 = (col & 63) >> 1;
          float2 csv = *(const float2*)(cs + ((size_t)t * 32 + i0) * 2);
          float r = (col & 1) ? (x * csv.x + xp * csv.y) : (x * csv.x - xp * csv.y);
          ((u16*)Cout)[(size_t)row * Nd + col] = f2bf(r);
        }
      }
}

// ---------------- segment compression, split-K MFMA (stage 1: partials) ----------------
__global__ __launch_bounds__(512) void compress_partial_kernel(
    const u16* __restrict__ kh, const u16* __restrict__ vh,
    const u16* __restrict__ wkcb, const u16* __restrict__ wvcb,
    float* __restrict__ part) {
  int mt = blockIdx.x, ksl = blockIdx.y, kv = blockIdx.z;
  const u16* src = kv ? vh : kh;
  const u16* W = kv ? wvcb : wkcb;
  int tid = threadIdx.x, lane = tid & 63, wv = tid >> 6;
  int l15 = lane & 15, lq = lane >> 4;
  int r = mt * 16 + l15;                             // row in [0,768)
  int nh = r / 6, s = r % 6;
  int n = nh >> 4, h = nh & 15;
  const u16* arow = src + ((size_t)(n * 2048 + s * 256)) * 1024 + h * 64;
  f32x4 acc[4] = {};
  int kbase = (ksl * 8 + wv) * 256;
#pragma unroll
  for (int ks = 0; ks < 8; ++ks) {
    int k0 = kbase + ks * 32;
    int tau = k0 >> 6, d0 = k0 & 63;
    bf16x8 a = *(const bf16x8*)(arow + (size_t)tau * 1024 + d0 + lq * 8);
#pragma unroll
    for (int nt = 0; nt < 4; ++nt) {
      bf16x8 b = *(const bf16x8*)(W + (size_t)(nt * 16 + l15) * 16384 + k0 + lq * 8);
      acc[nt] = mfma16(a, b, acc[nt]);
    }
  }
  __shared__ float red[8][16][68];                   // 68-stride: 2-way bank alias only (free)
#pragma unroll
  for (int nt = 0; nt < 4; ++nt)
#pragma unroll
    for (int i = 0; i < 4; ++i)
      red[wv][lq * 4 + i][nt * 16 + l15] = acc[nt][i];
  __syncthreads();
  int row = tid >> 5, o0 = (tid & 31) * 2;           // 512 threads -> 16 rows x 32 pairs
  float v0 = 0.f, v1 = 0.f;
#pragma unroll
  for (int w8 = 0; w8 < 8; ++w8) { v0 += red[w8][row][o0]; v1 += red[w8][row][o0 + 1]; }
  size_t base = ((size_t)(kv * 8 + ksl) * 768 + mt * 16 + row) * 64 + o0;
  part[base] = v0;
  part[base + 1] = v1;
}

// ---------------- merged: compress finalize (sum slices, bias, elu, scatter) + copy recent ------------
__global__ __launch_bounds__(256) void finalize_copy_kernel(
    const float* __restrict__ part, const float* __restrict__ bkc, const float* __restrict__ bvc,
    const u16* __restrict__ kh, const u16* __restrict__ vh,
    u16* __restrict__ kp, u16* __restrict__ vtp) {
  int bid = blockIdx.x;
  if (bid < 2280) {                                  // K rows T=6..575
    int u = bid * 256 + threadIdx.x;                 // = (nh*570 + (T-6))*8 + dq8
    int dq8 = u & 7; int rest = u >> 3; int Tm6 = rest % 570; int nh = rest / 570;
    if (nh >= 128) return;
    uint4 val = {0, 0, 0, 0};
    if (Tm6 < 512) {
      int n = nh >> 4, h = nh & 15;
      val = *(const uint4*)&kh[((size_t)(n * 2048 + 1536 + Tm6)) * 1024 + h * 64 + dq8 * 8];
    }
    *(uint4*)&kp[((size_t)nh * 576 + 6 + Tm6) * 64 + dq8 * 8] = val;
  } else if (bid < 4584) {                           // V^T cols
    int u = (bid - 2280) * 256 + threadIdx.x;        // = (nh*72 + tch)*64 + d
    int d = u & 63; int rest = u >> 6; int tch = rest % 72; int nh = rest / 72;
    if (nh >= 128) return;
    int n = nh >> 4, h = nh & 15;
#pragma unroll
    for (int ii = 0; ii < 8; ++ii) {
      int T = tch * 8 + ii;
      if (T < 6) continue;                           // written by compression
      u16 v = 0;
      if (T < 518) v = vh[((size_t)(n * 2048 + 1536 + (T - 6))) * 1024 + h * 64 + d];
      vtp[((size_t)nh * 64 + d) * 576 + T] = v;
    }
  } else {                                           // compress finalize
    int b2 = bid - 4584;                             // 0..383
    int kv = b2 >= 192;
    int id = (kv ? b2 - 192 : b2) * 256 + threadIdx.x;   // [0, 49152)
    int r = id >> 6, o = id & 63;
    float v = kv ? bvc[o] : bkc[o];
#pragma unroll
    for (int s8 = 0; s8 < 8; ++s8) v += part[((size_t)(kv * 8 + s8) * 768 + r) * 64 + o];
    v = v > 0.f ? v : expm1f(v);                     // elu
    int nh = r / 6, s = r % 6;
    if (kv) vtp[((size_t)nh * 64 + o) * 576 + s] = f2bf(v);
    else    kp[((size_t)nh * 576 + s) * 64 + o] = f2bf(v);
  }
}

// ---------------- fused attention: per (n,h,128 q-rows), 512 thr / 8 waves x 16 rows each --------------
// Fixed softmax max=30; XCD-pinning grid (h, qt, n); causal wave skip.
__global__ __launch_bounds__(512) void attn_kernel(const u16* __restrict__ qc, const u16* __restrict__ Kp,
                                                   const u16* __restrict__ VTp, u16* __restrict__ ao) {
  int h = blockIdx.x, qt = blockIdx.y, n = blockIdx.z;
  int tid = threadIdx.x, lane = tid & 63, wv = tid >> 6;   // wv 0..7
  int l15 = lane & 15, lq = lane >> 4;
  __shared__ u16 KS[4096], VS[4096];                 // 64x64 bf16 chunks, row-XOR-swizzled
  __shared__ float PS[8][1088];                      // per-wave P [16 rows][68 f32]
  int q0 = qt * 128 + wv * 16;
  const u16* qrowp = qc + ((size_t)(n * 2048 + q0 + l15)) * 1024 + h * 64;
  bf16x8 aq0 = *(const bf16x8*)(qrowp + lq * 8);
  bf16x8 aq1 = *(const bf16x8*)(qrowp + 32 + lq * 8);
  const u16* Kph = Kp + (size_t)(n * 16 + h) * 576 * 64;
  const u16* Vph = VTp + (size_t)(n * 16 + h) * 64 * 576;
  f32x4 oa[4] = {};
  float rs[4] = {0.f, 0.f, 0.f, 0.f};
  float* PSW = &PS[wv][0];
  const float C1 = 0.012022458674074693f;            // 0.125 * (2/30) * log2(e)
  const float C2 = -86.56170245333781f;              // -60 * log2(e)
  int nchunks = min(2 * qt + 2, 9);                  // block rows < 128(qt+1)
  int dcw = 2 * qt + (wv >> 2);                      // wave's diagonal chunk
  int srow = tid >> 3, sq = tid & 7;
  int ksw = srow * 64 + ((sq ^ (srow & 7)) * 8);
  uint4 kr, vr;
  {
    kr = *(const uint4*)&Kph[(size_t)srow * 64 + sq * 8];
    vr = *(const uint4*)&Vph[(size_t)srow * 576 + sq * 8];
  }
  for (int tc = 0; tc < nchunks; ++tc) {
    __syncthreads();                                 // prev iter's LDS reads done
    *(uint4*)&KS[ksw] = kr;
    *(uint4*)&VS[ksw] = vr;
    if (tc + 1 < nchunks) {                          // async prefetch of next chunk
      int Tb = (tc + 1) * 64;
      kr = *(const uint4*)&Kph[(size_t)(Tb + srow) * 64 + sq * 8];
      vr = *(const uint4*)&Vph[(size_t)srow * 576 + Tb + sq * 8];
    }
    __syncthreads();                                 // LDS writes visible
    if (tc > dcw) continue;                          // wave-uniform causal skip
    f32x4 sv[4];
    __builtin_amdgcn_s_setprio(1);
#pragma unroll
    for (int tt = 0; tt < 4; ++tt) {
      int row = tt * 16 + l15, r7 = row & 7;
      bf16x8 b0 = *(const bf16x8*)&KS[row * 64 + ((lq ^ r7) * 8)];
      bf16x8 b1 = *(const bf16x8*)&KS[row * 64 + (((4 | lq) ^ r7) * 8)];
      f32x4 c = {0.f, 0.f, 0.f, 0.f};
      c = mfma16(aq0, b0, c);
      c = mfma16(aq1, b1, c);
      sv[tt] = c;
    }
    __builtin_amdgcn_s_setprio(0);
    float p[4][4];
    bool needmask = (tc == dcw) || (tc == 8);
    if (needmask) {
      int qb = q0 + lq * 4;
      int Tbase = tc * 64;
#pragma unroll
      for (int tt = 0; tt < 4; ++tt) {
        int T = Tbase + tt * 16 + l15;
        bool tval = (T < 518);
#pragma unroll
        for (int i = 0; i < 4; ++i) {
          float e = __builtin_amdgcn_exp2f(sv[tt][i] * C1);
          float pe = __builtin_amdgcn_exp2f(C2 * __builtin_amdgcn_rcpf(e + 1.f));
          bool ok = tval && (T <= qb + i);
          pe = ok ? pe : 0.f;
          p[tt][i] = pe;
          rs[i] += pe;
        }
      }
    } else {
#pragma unroll
      for (int tt = 0; tt < 4; ++tt)
#pragma unroll
        for (int i = 0; i < 4; ++i) {
          float e = __builtin_amdgcn_exp2f(sv[tt][i] * C1);
          float pe = __builtin_amdgcn_exp2f(C2 * __builtin_amdgcn_rcpf(e + 1.f));
          p[tt][i] = pe;
          rs[i] += pe;
        }
    }
#pragma unroll
    for (int tt = 0; tt < 4; ++tt)
#pragma unroll
      for (int i = 0; i < 4; ++i)
        PSW[(lq * 4 + i) * 68 + tt * 16 + l15] = p[tt][i];
    const float* prow = PSW + l15 * 68;
    f32x4 r0a = *(const f32x4*)(prow + lq * 8);
    f32x4 r0b = *(const f32x4*)(prow + lq * 8 + 4);
    f32x4 r1a = *(const f32x4*)(prow + lq * 8 + 32);
    f32x4 r1b = *(const f32x4*)(prow + lq * 8 + 36);
    bf16x8 pa0 = pk8(r0a, r0b);
    bf16x8 pa1 = pk8(r1a, r1b);
    __builtin_amdgcn_s_setprio(1);
#pragma unroll
    for (int ct = 0; ct < 4; ++ct) {
      int row = ct * 16 + l15, r7 = row & 7;
      bf16x8 bv0 = *(const bf16x8*)&VS[row * 64 + ((lq ^ r7) * 8)];
      bf16x8 bv1 = *(const bf16x8*)&VS[row * 64 + (((4 | lq) ^ r7) * 8)];
      oa[ct] = mfma16(pa0, bv0, oa[ct]);
      oa[ct] = mfma16(pa1, bv1, oa[ct]);
    }
    __builtin_amdgcn_s_setprio(0);
  }
#pragma unroll
  for (int i = 0; i < 4; ++i)
#pragma unroll
    for (int off = 1; off < 16; off <<= 1) rs[i] += __shfl_xor(rs[i], off, 64);
  u16* aop = ao + ((size_t)(n * 2048)) * 1024 + h * 64;
#pragma unroll
  for (int i = 0; i < 4; ++i) {
    float inv = 1.0f / rs[i];
    int q = q0 + lq * 4 + i;
#pragma unroll
    for (int ct = 0; ct < 4; ++ct) {
      int dv = ct * 16 + l15;
      aop[(size_t)q * 1024 + dv] = f2bf(oa[ct][i] * inv);
    }
  }
}

extern "C" void kernel_launch(void* const* d_in, const int* in_sizes, int n_in,
                              void* d_out, int out_size, void* d_ws, size_t ws_size,
                              hipStream_t stream) {
  const float* q_in = (const float*)d_in[0];
  const float* k_in = (const float*)d_in[1];
  const float* v_in = (const float*)d_in[2];
  const float* ln_w = (const float*)d_in[3];
  const float* ln_b = (const float*)d_in[4];
  const float* Wq = (const float*)d_in[5];
  const float* Wk = (const float*)d_in[6];
  const float* Wv = (const float*)d_in[7];
  const float* Wo = (const float*)d_in[8];
  const float* Wkc = (const float*)d_in[9];
  const float* bkc = (const float*)d_in[10];
  const float* Wvc = (const float*)d_in[11];
  const float* bvc = (const float*)d_in[12];

  char* ws = (char*)d_ws;
  const size_t MB = 1u << 20;
  u16* wqe = (u16*)(ws + 0 * MB);
  u16* wkb = (u16*)(ws + 2 * MB);
  u16* wvb = (u16*)(ws + 4 * MB);
  u16* wob = (u16*)(ws + 6 * MB);
  u16* wkcb = (u16*)(ws + 8 * MB);
  u16* wvcb = (u16*)(ws + 10 * MB);
  float* csb = (float*)(ws + 12 * MB);   // 512KB float2 cos/sin table
  u16* xn = (u16*)(ws + 13 * MB);    // 32MB: LN(v) staging; dead after gemm-v -> reused for partials
  float* partf = (float*)(ws + 13 * MB);
  u16* qcb = (u16*)(ws + 45 * MB);   // 32MB
  u16* khb = (u16*)(ws + 77 * MB);   // 32MB
  u16* vhb = (u16*)(ws + 109 * MB);  // 32MB
  u16* kp = (u16*)(ws + 141 * MB);   // 9.0MB
  u16* vtp = (u16*)(ws + 141 * MB + 9437184);
  u16* aob = khb;                    // kh dead once attention runs
  // d_out (64MB f32) doubles as LN scratch for q and k (2 x 32MB bf16);
  // the final GEMM fully overwrites it.
  u16* xq = (u16*)d_out;
  u16* xk = ((u16*)d_out) + 16777216;

  // merged weight prep + 3x layernorm (one launch)
  prep_ln_kernel<<<55552, 256, 0, stream>>>(Wq, Wk, Wv, Wo, Wkc, Wvc,
                                            wqe, wkb, wvb, wob, wkcb, wvcb, csb,
                                            q_in, k_in, v_in, ln_w, ln_b, xq, xk, xn);

  dim3 gg(64, 8);                    // x = 256-row tile (x%8 pins row-band to one XCD), y = col tile
  gemm_nt<2><<<gg, 512, 0, stream>>>(xq, wqe, qcb, 16384, 1024, 1024, csb);   // Q + RoPE
  gemm_nt<2><<<gg, 512, 0, stream>>>(xk, wkb, khb, 16384, 1024, 1024, csb);   // K + RoPE
  gemm_nt<0><<<gg, 512, 0, stream>>>(xn, wvb, vhb, 16384, 1024, 1024, csb);   // V

  compress_partial_kernel<<<dim3(48, 8, 2), 512, 0, stream>>>(khb, vhb, wkcb, wvcb, partf);
  finalize_copy_kernel<<<4968, 256, 0, stream>>>(partf, bkc, bvc, khb, vhb, kp, vtp);
  attn_kernel<<<dim3(16, 16, 8), 512, 0, stream>>>(qcb, kp, vtp, aob);
  gemm_nt<1><<<gg, 512, 0, stream>>>(aob, wob, (float*)d_out, 16384, 1024, 1024, csb);
}

// Round 17
// 369.603 us; speedup vs baseline: 1.1614x; 1.0171x over previous
//
#include <hip/hip_runtime.h>
#include <stdint.h>

#define DEV static __device__ __forceinline__

typedef unsigned short u16;
typedef unsigned int u32;
typedef __attribute__((ext_vector_type(4))) float f32x4;
typedef __attribute__((ext_vector_type(8))) short bf16x8;

DEV float bf2f(u16 u) { u32 x = ((u32)u) << 16; float f; __builtin_memcpy(&f, &x, 4); return f; }
DEV u16 f2bf(float f) { u32 x; __builtin_memcpy(&x, &f, 4); x = x + 0x7fffu + ((x >> 16) & 1u); return (u16)(x >> 16); }
DEV float lo16(u32 p) { u32 x = p << 16; float f; __builtin_memcpy(&f, &x, 4); return f; }
DEV float hi16(u32 p) { u32 x = p & 0xffff0000u; float f; __builtin_memcpy(&f, &x, 4); return f; }

DEV u32 cvtpk(float lo, float hi) {        // one v_cvt_pk_bf16_f32 (no builtin on gfx950)
  u32 r; asm("v_cvt_pk_bf16_f32 %0, %1, %2" : "=v"(r) : "v"(lo), "v"(hi)); return r;
}
DEV bf16x8 pk8(f32x4 a, f32x4 b) {
  union { u32 u[4]; bf16x8 v; } x;
  x.u[0] = cvtpk(a[0], a[1]); x.u[1] = cvtpk(a[2], a[3]);
  x.u[2] = cvtpk(b[0], b[1]); x.u[3] = cvtpk(b[2], b[3]);
  return x.v;
}
DEV uint2 pk4(float4 a) {                  // float4 -> 4 bf16 (2 u32)
  uint2 r; r.x = cvtpk(a.x, a.y); r.y = cvtpk(a.z, a.w); return r;
}

DEV f32x4 mfma16(bf16x8 a, bf16x8 b, f32x4 c) {
  return __builtin_amdgcn_mfma_f32_16x16x32_bf16(a, b, c, 0, 0, 0);
}

DEV void gl_lds16(const u16* g, u16* l) {
  __builtin_amdgcn_global_load_lds((const __attribute__((address_space(1))) void*)g,
                                   (__attribute__((address_space(3))) void*)l, 16, 0, 0);
}

// ---------------- merged: weight prep (casts + Wq group-sum + rope table) AND 3x layernorm -----------
// blocks 0..6143: weight casts; 6144..6399: rope table; 6400..18687: LN (wave-per-row, 4 rows/block).
__global__ __launch_bounds__(256) void prep_ln_kernel(
    const float* __restrict__ Wq, const float* __restrict__ Wk, const float* __restrict__ Wv,
    const float* __restrict__ Wo, const float* __restrict__ Wkc, const float* __restrict__ Wvc,
    u16* __restrict__ wqe, u16* __restrict__ wkb, u16* __restrict__ wvb,
    u16* __restrict__ wob, u16* __restrict__ wkcb, u16* __restrict__ wvcb,
    float* __restrict__ cs,
    const float* __restrict__ xq, const float* __restrict__ xk, const float* __restrict__ xv,
    const float* __restrict__ lnw, const float* __restrict__ lnb,
    u16* __restrict__ oq, u16* __restrict__ ok, u16* __restrict__ ov) {
  int b = blockIdx.x;
  int tid = threadIdx.x;
  if (b < 6144) {
    int which = b >> 10;                             // 0..5
    int id = (b & 1023) * 256 + tid;                 // 262144 float4 units each
    const float* src; u16* dst;
    switch (which) {
      case 0: src = Wq;  dst = wqe;  break;
      case 1: src = Wk;  dst = wkb;  break;
      case 2: src = Wv;  dst = wvb;  break;
      case 3: src = Wo;  dst = wob;  break;
      case 4: src = Wkc; dst = wkcb; break;
      default: src = Wvc; dst = wvcb; break;
    }
    float4 a = ((const float4*)src)[id];
    if (which == 0) {
      float4 c = ((const float4*)Wq)[id + 262144];   // second GQA group slice
      a.x += c.x; a.y += c.y; a.z += c.z; a.w += c.w;
    }
    *(uint2*)(((u16*)dst) + id * 4) = pk4(a);
    return;
  }
  if (b < 6400) {
    int id = (b - 6144) * 256 + tid;                 // 65536 = 2048*32
    int t = id >> 5, i = id & 31;
    double ang = (double)t * pow(10000.0, -(double)(2 * i) / 64.0);
    cs[id * 2] = (float)cos(ang);
    cs[id * 2 + 1] = (float)sin(ang);
    return;
  }
  // ---- LN: one wave per row, no LDS, no barrier ----
  int r = (b - 6400) * 4 + (tid >> 6);               // 0..49151
  int which = r >> 14, row = r & 16383;
  const float* x = which == 0 ? xq : (which == 1 ? xk : xv);
  u16* out = which == 0 ? oq : (which == 1 ? ok : ov);
  int lane = tid & 63;
  const float* xr = x + (size_t)row * 1024 + lane * 4;
  float4 v0 = *(const float4*)(xr);
  float4 v1 = *(const float4*)(xr + 256);
  float4 v2 = *(const float4*)(xr + 512);
  float4 v3 = *(const float4*)(xr + 768);
  float s = (v0.x + v0.y + v0.z + v0.w) + (v1.x + v1.y + v1.z + v1.w)
          + (v2.x + v2.y + v2.z + v2.w) + (v3.x + v3.y + v3.z + v3.w);
  float s2 = v0.x * v0.x + v0.y * v0.y + v0.z * v0.z + v0.w * v0.w;
  s2 += v1.x * v1.x + v1.y * v1.y + v1.z * v1.z + v1.w * v1.w;
  s2 += v2.x * v2.x + v2.y * v2.y + v2.z * v2.z + v2.w * v2.w;
  s2 += v3.x * v3.x + v3.y * v3.y + v3.z * v3.z + v3.w * v3.w;
#pragma unroll
  for (int off = 32; off; off >>= 1) { s += __shfl_xor(s, off, 64); s2 += __shfl_xor(s2, off, 64); }
  float mu = s * 0.0009765625f;
  float var = s2 * 0.0009765625f - mu * mu;
  float rstd = rsqrtf(var + 1e-5f);
  u16* orow = out + (size_t)row * 1024 + lane * 4;
#pragma unroll
  for (int j = 0; j < 4; ++j) {
    float4 v = j == 0 ? v0 : (j == 1 ? v1 : (j == 2 ? v2 : v3));
    float4 wv = *(const float4*)(lnw + lane * 4 + j * 256);
    float4 bv = *(const float4*)(lnb + lane * 4 + j * 256);
    float4 o;
    o.x = (v.x - mu) * rstd * wv.x + bv.x;
    o.y = (v.y - mu) * rstd * wv.y + bv.y;
    o.z = (v.z - mu) * rstd * wv.z + bv.z;
    o.w = (v.w - mu) * rstd * wv.w + bv.w;
    *(uint2*)(orow + j * 256) = pk4(o);
  }
}

// ---------------- NT GEMM: C[m][n] = sum_k A[m*K+k]*B[n*K+k]  (256x128 tile, BK=64, 512 thr) ----------
// 8 waves as 4M x 2N (64x64 per wave). Grid (x = M/256, y = N/128); bid%8 = x%8 pins the
// A row-band to one XCD (ONE A matrix per dispatch -- batching 3 thrashed L2, round-15 lesson).
// XOR swizzle on both global source and read side.
// MODE: 0 = bf16 out, 1 = f32 out, 2 = bf16 out + fused interleaved RoPE (64-col heads, t=row%2048)
template <int MODE>
__global__ __launch_bounds__(512, 4) void gemm_nt(const u16* __restrict__ A, const u16* __restrict__ B,
                                                  void* __restrict__ Cout, int M, int Nd, int K,
                                                  const float* __restrict__ cs) {
  __shared__ u16 As[16384], Bs[8192];                // A: [256 rows][64 k], B: [128 rows][64 k]
  int tid = threadIdx.x, lane = tid & 63, wv = tid >> 6;   // wv 0..7
  int l15 = lane & 15, lq = lane >> 4;
  int bm = blockIdx.x * 256, bn = blockIdx.y * 128;
  int wm = (wv >> 1) * 64, wn = (wv & 1) * 64;
  int srow_in = lane >> 3, sslot = lane & 7;
  f32x4 acc[4][4] = {};
  for (int k0 = 0; k0 < K; k0 += 64) {
    __syncthreads();                                 // previous iter's LDS reads done
#pragma unroll
    for (int it = 0; it < 4; ++it) {                 // A: 32 slabs (8 rows x 64k each)
      int ia = it * 8 + wv;
      int row = ia * 8 + srow_in;                    // 0..255
      int gc = sslot ^ (row & 7);                    // pre-swizzled global chunk
      gl_lds16(A + (size_t)(bm + row) * K + k0 + gc * 8, &As[ia * 512]);
    }
#pragma unroll
    for (int it = 0; it < 2; ++it) {                 // B: 16 slabs
      int ia = it * 8 + wv;
      int row = ia * 8 + srow_in;                    // 0..127
      int gc = sslot ^ (row & 7);
      gl_lds16(B + (size_t)(bn + row) * K + k0 + gc * 8, &Bs[ia * 512]);
    }
    __syncthreads();                                 // vmcnt(0) drain before use
#pragma unroll
    for (int h = 0; h < 2; ++h) {
      bf16x8 af[4], bfr[4];
#pragma unroll
      for (int mt = 0; mt < 4; ++mt) {
        int r = wm + mt * 16 + l15;
        af[mt] = *(const bf16x8*)&As[r * 64 + (((h * 4 + lq) ^ (r & 7)) * 8)];
      }
#pragma unroll
      for (int nt = 0; nt < 4; ++nt) {
        int r = wn + nt * 16 + l15;
        bfr[nt] = *(const bf16x8*)&Bs[r * 64 + (((h * 4 + lq) ^ (r & 7)) * 8)];
      }
#pragma unroll
      for (int mt = 0; mt < 4; ++mt)
#pragma unroll
        for (int nt = 0; nt < 4; ++nt)
          acc[mt][nt] = mfma16(af[mt], bfr[nt], acc[mt][nt]);
    }
  }
#pragma unroll
  for (int mt = 0; mt < 4; ++mt)
#pragma unroll
    for (int nt = 0; nt < 4; ++nt)
#pragma unroll
      for (int i = 0; i < 4; ++i) {
        int row = bm + wm + mt * 16 + lq * 4 + i;
        int col = bn + wn + nt * 16 + l15;
        float x = acc[mt][nt][i];
        if (MODE == 1) {
          ((float*)Cout)[(size_t)row * Nd + col] = x;
        } else if (MODE == 0) {
          ((u16*)Cout)[(size_t)row * Nd + col] = f2bf(x);
        } else {
          float xp = __shfl_xor(x, 1, 64);           // partner column (col^1), lane l15^1
          int t = row & 2047;
          int i0 = (col & 63) >> 1;
          float2 csv = *(const float2*)(cs + ((size_t)t * 32 + i0) * 2);
          float r = (col & 1) ? (x * csv.x + xp * csv.y) : (x * csv.x - xp * csv.y);
          ((u16*)Cout)[(size_t)row * Nd + col] = f2bf(r);
        }
      }
}

// ---------------- segment compression, split-K MFMA (stage 1: partials) ----------------
__global__ __launch_bounds__(512) void compress_partial_kernel(
    const u16* __restrict__ kh, const u16* __restrict__ vh,
    const u16* __restrict__ wkcb, const u16* __restrict__ wvcb,
    float* __restrict__ part) {
  int mt = blockIdx.x, ksl = blockIdx.y, kv = blockIdx.z;
  const u16* src = kv ? vh : kh;
  const u16* W = kv ? wvcb : wkcb;
  int tid = threadIdx.x, lane = tid & 63, wv = tid >> 6;
  int l15 = lane & 15, lq = lane >> 4;
  int r = mt * 16 + l15;                             // row in [0,768)
  int nh = r / 6, s = r % 6;
  int n = nh >> 4, h = nh & 15;
  const u16* arow = src + ((size_t)(n * 2048 + s * 256)) * 1024 + h * 64;
  f32x4 acc[4] = {};
  int kbase = (ksl * 8 + wv) * 256;
#pragma unroll
  for (int ks = 0; ks < 8; ++ks) {
    int k0 = kbase + ks * 32;
    int tau = k0 >> 6, d0 = k0 & 63;
    bf16x8 a = *(const bf16x8*)(arow + (size_t)tau * 1024 + d0 + lq * 8);
#pragma unroll
    for (int nt = 0; nt < 4; ++nt) {
      bf16x8 b = *(const bf16x8*)(W + (size_t)(nt * 16 + l15) * 16384 + k0 + lq * 8);
      acc[nt] = mfma16(a, b, acc[nt]);
    }
  }
  __shared__ float red[8][16][68];                   // 68-stride: 2-way bank alias only (free)
#pragma unroll
  for (int nt = 0; nt < 4; ++nt)
#pragma unroll
    for (int i = 0; i < 4; ++i)
      red[wv][lq * 4 + i][nt * 16 + l15] = acc[nt][i];
  __syncthreads();
  int row = tid >> 5, o0 = (tid & 31) * 2;           // 512 threads -> 16 rows x 32 pairs
  float v0 = 0.f, v1 = 0.f;
#pragma unroll
  for (int w8 = 0; w8 < 8; ++w8) { v0 += red[w8][row][o0]; v1 += red[w8][row][o0 + 1]; }
  size_t base = ((size_t)(kv * 8 + ksl) * 768 + mt * 16 + row) * 64 + o0;
  part[base] = v0;
  part[base + 1] = v1;
}

// ---------------- merged: compress finalize (sum slices, bias, elu, scatter) + copy recent ------------
__global__ __launch_bounds__(256) void finalize_copy_kernel(
    const float* __restrict__ part, const float* __restrict__ bkc, const float* __restrict__ bvc,
    const u16* __restrict__ kh, const u16* __restrict__ vh,
    u16* __restrict__ kp, u16* __restrict__ vtp) {
  int bid = blockIdx.x;
  if (bid < 2280) {                                  // K rows T=6..575
    int u = bid * 256 + threadIdx.x;                 // = (nh*570 + (T-6))*8 + dq8
    int dq8 = u & 7; int rest = u >> 3; int Tm6 = rest % 570; int nh = rest / 570;
    if (nh >= 128) return;
    uint4 val = {0, 0, 0, 0};
    if (Tm6 < 512) {
      int n = nh >> 4, h = nh & 15;
      val = *(const uint4*)&kh[((size_t)(n * 2048 + 1536 + Tm6)) * 1024 + h * 64 + dq8 * 8];
    }
    *(uint4*)&kp[((size_t)nh * 576 + 6 + Tm6) * 64 + dq8 * 8] = val;
  } else if (bid < 4584) {                           // V^T cols
    int u = (bid - 2280) * 256 + threadIdx.x;        // = (nh*72 + tch)*64 + d
    int d = u & 63; int rest = u >> 6; int tch = rest % 72; int nh = rest / 72;
    if (nh >= 128) return;
    int n = nh >> 4, h = nh & 15;
#pragma unroll
    for (int ii = 0; ii < 8; ++ii) {
      int T = tch * 8 + ii;
      if (T < 6) continue;                           // written by compression
      u16 v = 0;
      if (T < 518) v = vh[((size_t)(n * 2048 + 1536 + (T - 6))) * 1024 + h * 64 + d];
      vtp[((size_t)nh * 64 + d) * 576 + T] = v;
    }
  } else {                                           // compress finalize
    int b2 = bid - 4584;                             // 0..383
    int kv = b2 >= 192;
    int id = (kv ? b2 - 192 : b2) * 256 + threadIdx.x;   // [0, 49152)
    int r = id >> 6, o = id & 63;
    float v = kv ? bvc[o] : bkc[o];
#pragma unroll
    for (int s8 = 0; s8 < 8; ++s8) v += part[((size_t)(kv * 8 + s8) * 768 + r) * 64 + o];
    v = v > 0.f ? v : expm1f(v);                     // elu
    int nh = r / 6, s = r % 6;
    if (kv) vtp[((size_t)nh * 64 + o) * 576 + s] = f2bf(v);
    else    kp[((size_t)nh * 576 + s) * 64 + o] = f2bf(v);
  }
}

// ---------------- fused attention: per (n,h,128 q-rows), 512 thr / 8 waves x 16 rows each --------------
// Fixed softmax max=30; XCD-pinning grid (h, qt, n); causal wave skip.
__global__ __launch_bounds__(512) void attn_kernel(const u16* __restrict__ qc, const u16* __restrict__ Kp,
                                                   const u16* __restrict__ VTp, u16* __restrict__ ao) {
  int h = blockIdx.x, qt = blockIdx.y, n = blockIdx.z;
  int tid = threadIdx.x, lane = tid & 63, wv = tid >> 6;   // wv 0..7
  int l15 = lane & 15, lq = lane >> 4;
  __shared__ u16 KS[4096], VS[4096];                 // 64x64 bf16 chunks, row-XOR-swizzled
  __shared__ float PS[8][1088];                      // per-wave P [16 rows][68 f32]
  int q0 = qt * 128 + wv * 16;
  const u16* qrowp = qc + ((size_t)(n * 2048 + q0 + l15)) * 1024 + h * 64;
  bf16x8 aq0 = *(const bf16x8*)(qrowp + lq * 8);
  bf16x8 aq1 = *(const bf16x8*)(qrowp + 32 + lq * 8);
  const u16* Kph = Kp + (size_t)(n * 16 + h) * 576 * 64;
  const u16* Vph = VTp + (size_t)(n * 16 + h) * 64 * 576;
  f32x4 oa[4] = {};
  float rs[4] = {0.f, 0.f, 0.f, 0.f};
  float* PSW = &PS[wv][0];
  const float C1 = 0.012022458674074693f;            // 0.125 * (2/30) * log2(e)
  const float C2 = -86.56170245333781f;              // -60 * log2(e)
  int nchunks = min(2 * qt + 2, 9);                  // block rows < 128(qt+1)
  int dcw = 2 * qt + (wv >> 2);                      // wave's diagonal chunk
  int srow = tid >> 3, sq = tid & 7;
  int ksw = srow * 64 + ((sq ^ (srow & 7)) * 8);
  uint4 kr, vr;
  {
    kr = *(const uint4*)&Kph[(size_t)srow * 64 + sq * 8];
    vr = *(const uint4*)&Vph[(size_t)srow * 576 + sq * 8];
  }
  for (int tc = 0; tc < nchunks; ++tc) {
    __syncthreads();                                 // prev iter's LDS reads done
    *(uint4*)&KS[ksw] = kr;
    *(uint4*)&VS[ksw] = vr;
    if (tc + 1 < nchunks) {                          // async prefetch of next chunk
      int Tb = (tc + 1) * 64;
      kr = *(const uint4*)&Kph[(size_t)(Tb + srow) * 64 + sq * 8];
      vr = *(const uint4*)&Vph[(size_t)srow * 576 + Tb + sq * 8];
    }
    __syncthreads();                                 // LDS writes visible
    if (tc > dcw) continue;                          // wave-uniform causal skip
    f32x4 sv[4];
    __builtin_amdgcn_s_setprio(1);
#pragma unroll
    for (int tt = 0; tt < 4; ++tt) {
      int row = tt * 16 + l15, r7 = row & 7;
      bf16x8 b0 = *(const bf16x8*)&KS[row * 64 + ((lq ^ r7) * 8)];
      bf16x8 b1 = *(const bf16x8*)&KS[row * 64 + (((4 | lq) ^ r7) * 8)];
      f32x4 c = {0.f, 0.f, 0.f, 0.f};
      c = mfma16(aq0, b0, c);
      c = mfma16(aq1, b1, c);
      sv[tt] = c;
    }
    __builtin_amdgcn_s_setprio(0);
    float p[4][4];
    bool needmask = (tc == dcw) || (tc == 8);
    if (needmask) {
      int qb = q0 + lq * 4;
      int Tbase = tc * 64;
#pragma unroll
      for (int tt = 0; tt < 4; ++tt) {
        int T = Tbase + tt * 16 + l15;
        bool tval = (T < 518);
#pragma unroll
        for (int i = 0; i < 4; ++i) {
          float e = __builtin_amdgcn_exp2f(sv[tt][i] * C1);
          float pe = __builtin_amdgcn_exp2f(C2 * __builtin_amdgcn_rcpf(e + 1.f));
          bool ok = tval && (T <= qb + i);
          pe = ok ? pe : 0.f;
          p[tt][i] = pe;
          rs[i] += pe;
        }
      }
    } else {
#pragma unroll
      for (int tt = 0; tt < 4; ++tt)
#pragma unroll
        for (int i = 0; i < 4; ++i) {
          float e = __builtin_amdgcn_exp2f(sv[tt][i] * C1);
          float pe = __builtin_amdgcn_exp2f(C2 * __builtin_amdgcn_rcpf(e + 1.f));
          p[tt][i] = pe;
          rs[i] += pe;
        }
    }
#pragma unroll
    for (int tt = 0; tt < 4; ++tt)
#pragma unroll
      for (int i = 0; i < 4; ++i)
        PSW[(lq * 4 + i) * 68 + tt * 16 + l15] = p[tt][i];
    const float* prow = PSW + l15 * 68;
    f32x4 r0a = *(const f32x4*)(prow + lq * 8);
    f32x4 r0b = *(const f32x4*)(prow + lq * 8 + 4);
    f32x4 r1a = *(const f32x4*)(prow + lq * 8 + 32);
    f32x4 r1b = *(const f32x4*)(prow + lq * 8 + 36);
    bf16x8 pa0 = pk8(r0a, r0b);
    bf16x8 pa1 = pk8(r1a, r1b);
    __builtin_amdgcn_s_setprio(1);
#pragma unroll
    for (int ct = 0; ct < 4; ++ct) {
      int row = ct * 16 + l15, r7 = row & 7;
      bf16x8 bv0 = *(const bf16x8*)&VS[row * 64 + ((lq ^ r7) * 8)];
      bf16x8 bv1 = *(const bf16x8*)&VS[row * 64 + (((4 | lq) ^ r7) * 8)];
      oa[ct] = mfma16(pa0, bv0, oa[ct]);
      oa[ct] = mfma16(pa1, bv1, oa[ct]);
    }
    __builtin_amdgcn_s_setprio(0);
  }
#pragma unroll
  for (int i = 0; i < 4; ++i)
#pragma unroll
    for (int off = 1; off < 16; off <<= 1) rs[i] += __shfl_xor(rs[i], off, 64);
  u16* aop = ao + ((size_t)(n * 2048)) * 1024 + h * 64;
#pragma unroll
  for (int i = 0; i < 4; ++i) {
    float inv = 1.0f / rs[i];
    int q = q0 + lq * 4 + i;
#pragma unroll
    for (int ct = 0; ct < 4; ++ct) {
      int dv = ct * 16 + l15;
      aop[(size_t)q * 1024 + dv] = f2bf(oa[ct][i] * inv);
    }
  }
}

extern "C" void kernel_launch(void* const* d_in, const int* in_sizes, int n_in,
                              void* d_out, int out_size, void* d_ws, size_t ws_size,
                              hipStream_t stream) {
  const float* q_in = (const float*)d_in[0];
  const float* k_in = (const float*)d_in[1];
  const float* v_in = (const float*)d_in[2];
  const float* ln_w = (const float*)d_in[3];
  const float* ln_b = (const float*)d_in[4];
  const float* Wq = (const float*)d_in[5];
  const float* Wk = (const float*)d_in[6];
  const float* Wv = (const float*)d_in[7];
  const float* Wo = (const float*)d_in[8];
  const float* Wkc = (const float*)d_in[9];
  const float* bkc = (const float*)d_in[10];
  const float* Wvc = (const float*)d_in[11];
  const float* bvc = (const float*)d_in[12];

  char* ws = (char*)d_ws;
  const size_t MB = 1u << 20;
  u16* wqe = (u16*)(ws + 0 * MB);
  u16* wkb = (u16*)(ws + 2 * MB);
  u16* wvb = (u16*)(ws + 4 * MB);
  u16* wob = (u16*)(ws + 6 * MB);
  u16* wkcb = (u16*)(ws + 8 * MB);
  u16* wvcb = (u16*)(ws + 10 * MB);
  float* csb = (float*)(ws + 12 * MB);   // 512KB float2 cos/sin table
  u16* xn = (u16*)(ws + 13 * MB);    // 32MB: LN(v) staging; dead after gemm-v -> reused for partials
  float* partf = (float*)(ws + 13 * MB);
  u16* qcb = (u16*)(ws + 45 * MB);   // 32MB
  u16* khb = (u16*)(ws + 77 * MB);   // 32MB
  u16* vhb = (u16*)(ws + 109 * MB);  // 32MB
  u16* kp = (u16*)(ws + 141 * MB);   // 9.0MB
  u16* vtp = (u16*)(ws + 141 * MB + 9437184);
  u16* aob = khb;                    // kh dead once attention runs
  // d_out (64MB f32) doubles as LN scratch for q and k (2 x 32MB bf16);
  // the final GEMM fully overwrites it.
  u16* xq = (u16*)d_out;
  u16* xk = ((u16*)d_out) + 16777216;

  // merged weight prep + 3x layernorm (one launch; LN is wave-per-row)
  prep_ln_kernel<<<18688, 256, 0, stream>>>(Wq, Wk, Wv, Wo, Wkc, Wvc,
                                            wqe, wkb, wvb, wob, wkcb, wvcb, csb,
                                            q_in, k_in, v_in, ln_w, ln_b, xq, xk, xn);

  dim3 gg(64, 8);                    // x = 256-row tile (x%8 pins row-band to one XCD), y = col tile
  gemm_nt<2><<<gg, 512, 0, stream>>>(xq, wqe, qcb, 16384, 1024, 1024, csb);   // Q + RoPE
  gemm_nt<2><<<gg, 512, 0, stream>>>(xk, wkb, khb, 16384, 1024, 1024, csb);   // K + RoPE
  gemm_nt<0><<<gg, 512, 0, stream>>>(xn, wvb, vhb, 16384, 1024, 1024, csb);   // V

  compress_partial_kernel<<<dim3(48, 8, 2), 512, 0, stream>>>(khb, vhb, wkcb, wvcb, partf);
  finalize_copy_kernel<<<4968, 256, 0, stream>>>(partf, bkc, bvc, khb, vhb, kp, vtp);
  attn_kernel<<<dim3(16, 16, 8), 512, 0, stream>>>(qcb, kp, vtp, aob);
  gemm_nt<1><<<gg, 512, 0, stream>>>(aob, wob, (float*)d_out, 16384, 1024, 1024, csb);
}